// Round 2
// baseline (2202.200 us; speedup 1.0000x reference)
//
#include <hip/hip_runtime.h>
#include <math.h>
#include <stdint.h>

namespace {

constexpr int B_ = 2, D_ = 2048, S_ = 128, A_ = 1536, T_ = 512;
constexpr int HQ_ = 16, HKV_ = 4, HD_ = 128, FF_ = 8192, L_ = 2;
constexpr float NEG_ = -30000.0f, EPS_ = 1e-5f;
constexpr int TOK_ = B_ * S_;  // 256 tokens

typedef __attribute__((ext_vector_type(4))) float f32x4;
typedef __attribute__((ext_vector_type(8))) short s16x8;  // 8 bf16 (4 VGPRs)

// split fp32 -> (hi bf16, lo bf16) packed in one u32: low16=hi, high16=lo.
// hi = RNE bf16 of x; lo = RNE bf16 of (x - hi). Dropped lo*lo term in the
// GEMM is ~2^-18 relative -> effectively fp32-accurate.
__device__ __forceinline__ uint32_t bf16pair(float x) {
  uint32_t xi = __float_as_uint(x);
  uint32_t hi = (xi + 0x7FFFu + ((xi >> 16) & 1u)) >> 16;
  float hf = __uint_as_float(hi << 16);
  float r = x - hf;  // exact
  uint32_t ri = __float_as_uint(r);
  uint32_t lo = (ri + 0x7FFFu + ((ri >> 16) & 1u)) >> 16;
  return (hi & 0xFFFFu) | (lo << 16);
}

// unpack 8 interleaved u32 {hi,lo} -> hi-fragment and lo-fragment (bf16x8)
__device__ __forceinline__ void unpack8(uint4 q0, uint4 q1, s16x8& hi, s16x8& lo) {
  union U { uint32_t w[4]; s16x8 v; };
  U h, l;
  uint32_t u[8] = {q0.x, q0.y, q0.z, q0.w, q1.x, q1.y, q1.z, q1.w};
#pragma unroll
  for (int r = 0; r < 4; r++) {
    // v_perm_b32 pool: sel 0-3 = src1 bytes, sel 4-7 = src0 bytes
    h.w[r] = __builtin_amdgcn_perm(u[2 * r + 1], u[2 * r], 0x05040100u);
    l.w[r] = __builtin_amdgcn_perm(u[2 * r + 1], u[2 * r], 0x07060302u);
  }
  hi = h.v;
  lo = l.v;
}

// ---------------- RMSNorm ----------------
__global__ __launch_bounds__(256) void rms_sumsq(const float* __restrict__ x,
                                                 float* __restrict__ rsum) {
  int b = blockIdx.y, c = blockIdx.x;
  int tid = threadIdx.x;
  int s = tid & 127, dd = tid >> 7;
  const float* xp = x + ((size_t)b * D_ + c * 128) * S_ + s;
  float acc = 0.f;
  for (int d = dd; d < 128; d += 2) {
    float v = xp[(size_t)d * S_];
    acc += v * v;
  }
  __shared__ float lds[256];
  lds[tid] = acc;
  __syncthreads();
  if (dd == 0) atomicAdd(&rsum[b * S_ + s], lds[s] + lds[128 + s]);
}

__global__ __launch_bounds__(256) void rms_apply(const float* __restrict__ x,
                                                 const float* __restrict__ rsum,
                                                 const float* __restrict__ w,
                                                 float* __restrict__ out) {
  int i = blockIdx.x * 256 + threadIdx.x;
  int s = i & (S_ - 1);
  int d = (i / S_) & (D_ - 1);
  int b = i / (D_ * S_);
  float inv = rsqrtf(rsum[b * S_ + s] * (1.0f / D_) + EPS_);
  out[i] = x[i] * inv * w[d];
}

// ---------------- pack H: [b][K][S] fp32 -> Ht[b*128+s][K] u32{hi,lo} -------
// grid (K/64, B), block 256. Transpose via LDS.
__global__ __launch_bounds__(256) void pack_h(const float* __restrict__ H,
                                              uint32_t* __restrict__ Ht, int K) {
  int b = blockIdx.y;
  int k0 = blockIdx.x * 64;
  __shared__ uint32_t t[128][65];
  int tid = threadIdx.x;
  int s = tid & 127, kk = tid >> 7;
  const float* Hp = H + ((size_t)b * K + k0) * S_ + s;
  for (int k = kk; k < 64; k += 2) t[s][k] = bf16pair(Hp[(size_t)k * S_]);
  __syncthreads();
  int k2 = tid & 63, s2 = tid >> 6;
  uint32_t* Op = Ht + (size_t)(b * S_) * K + k0 + k2;
  for (int ss = s2; ss < 128; ss += 4) Op[(size_t)ss * K] = t[ss][k2];
}

// ---------------- split-bf16 MFMA GEMM ----------------
// C[b, m, s] (+)= sum_k W[k*M + m] * H[b, k, s]
// A-operand: W (convert+4x4 reg transpose at staging); B-operand: packed Ht.
// LDS layout per operand: [128 rows][32 u32] (u32 = {hi,lo} for one k),
// 16B granule-swizzled: granule' = granule ^ (row & 7)  (writes ~2-way,
// fragment ds_read_b128 conflict-free -- verified by hand bank arithmetic).
// grid (M/128, B, SK), block 256 (4 waves, 64x64 wave tiles), BK=32.
__global__ __launch_bounds__(256, 2) void gemm_mfma(
    const float* __restrict__ W, const uint32_t* __restrict__ Ht,
    float* __restrict__ Out, int M, int K, int KC, int accum) {
  __shared__ uint32_t As[128 * 32];
  __shared__ uint32_t Bs[128 * 32];
  int m0 = blockIdx.x * 128;
  int b = blockIdx.y;
  int k0 = blockIdx.z * KC;
  int tid = threadIdx.x;
  int lane = tid & 63, wave = tid >> 6;
  int wm = (wave >> 1) * 64, wn = (wave & 1) * 64;
  int lr = lane & 15, lg = lane >> 4;
  // A staging: thread loads 4 k-rows x float4 (4 m), transposes in regs
  int a_k4 = (tid >> 5) * 4;   // 0,4,...,28
  int a_m4 = (tid & 31) * 4;   // 0..124
  int ag = a_k4 >> 2;          // granule 0..7
  // B staging: 4 chunks of (row s, granule g)
  int b_g = tid & 3;
  int b_s = tid >> 2;  // 0..63
  const uint32_t* HtB = Ht + (size_t)(b * S_) * K;

  f32x4 acc[4][4];
  f32x4 zero = {0.f, 0.f, 0.f, 0.f};
#pragma unroll
  for (int i = 0; i < 4; i++)
#pragma unroll
    for (int j = 0; j < 4; j++) acc[i][j] = zero;

  for (int kk = k0; kk < k0 + KC; kk += 32) {
    // ---- stage A: W[k][M] -> As (convert + transpose) ----
    const float* Wp = W + (size_t)(kk + a_k4) * M + (m0 + a_m4);
    float4 w0 = *(const float4*)(Wp);
    float4 w1 = *(const float4*)(Wp + (size_t)M);
    float4 w2 = *(const float4*)(Wp + 2 * (size_t)M);
    float4 w3 = *(const float4*)(Wp + 3 * (size_t)M);
    {
      uint4 u;
      int m = a_m4;
      u.x = bf16pair(w0.x); u.y = bf16pair(w1.x); u.z = bf16pair(w2.x); u.w = bf16pair(w3.x);
      *(uint4*)&As[m * 32 + ((ag ^ (m & 7)) << 2)] = u;
      m = a_m4 + 1;
      u.x = bf16pair(w0.y); u.y = bf16pair(w1.y); u.z = bf16pair(w2.y); u.w = bf16pair(w3.y);
      *(uint4*)&As[m * 32 + ((ag ^ (m & 7)) << 2)] = u;
      m = a_m4 + 2;
      u.x = bf16pair(w0.z); u.y = bf16pair(w1.z); u.z = bf16pair(w2.z); u.w = bf16pair(w3.z);
      *(uint4*)&As[m * 32 + ((ag ^ (m & 7)) << 2)] = u;
      m = a_m4 + 3;
      u.x = bf16pair(w0.w); u.y = bf16pair(w1.w); u.z = bf16pair(w2.w); u.w = bf16pair(w3.w);
      *(uint4*)&As[m * 32 + ((ag ^ (m & 7)) << 2)] = u;
    }
    // ---- stage B: Ht rows (already k-contiguous) ----
#pragma unroll
    for (int c = 0; c < 2; c++)
#pragma unroll
      for (int d = 0; d < 2; d++) {
        int s = b_s + c * 64;
        int g = b_g + d * 4;
        uint4 v = *(const uint4*)&HtB[(size_t)s * K + kk + g * 4];
        *(uint4*)&Bs[s * 32 + ((g ^ (s & 7)) << 2)] = v;
      }
    __syncthreads();
    // ---- fragments ----
    s16x8 ah[4], al[4], bh[4], bl[4];
#pragma unroll
    for (int mi = 0; mi < 4; mi++) {
      int row = wm + mi * 16 + lr;
      const uint32_t* p = &As[row * 32];
      uint4 q0 = *(const uint4*)&p[(((lg << 1) ^ (row & 7)) << 2)];
      uint4 q1 = *(const uint4*)&p[((((lg << 1) | 1) ^ (row & 7)) << 2)];
      unpack8(q0, q1, ah[mi], al[mi]);
    }
#pragma unroll
    for (int ni = 0; ni < 4; ni++) {
      int row = wn + ni * 16 + lr;
      const uint32_t* p = &Bs[row * 32];
      uint4 q0 = *(const uint4*)&p[(((lg << 1) ^ (row & 7)) << 2)];
      uint4 q1 = *(const uint4*)&p[((((lg << 1) | 1) ^ (row & 7)) << 2)];
      unpack8(q0, q1, bh[ni], bl[ni]);
    }
    // ---- 3-product split accumulate (hi*hi, hi*lo, lo*hi) ----
#pragma unroll
    for (int mi = 0; mi < 4; mi++)
#pragma unroll
      for (int ni = 0; ni < 4; ni++)
        acc[mi][ni] = __builtin_amdgcn_mfma_f32_16x16x32_bf16(ah[mi], bh[ni],
                                                              acc[mi][ni], 0, 0, 0);
#pragma unroll
    for (int mi = 0; mi < 4; mi++)
#pragma unroll
      for (int ni = 0; ni < 4; ni++)
        acc[mi][ni] = __builtin_amdgcn_mfma_f32_16x16x32_bf16(ah[mi], bl[ni],
                                                              acc[mi][ni], 0, 0, 0);
#pragma unroll
    for (int mi = 0; mi < 4; mi++)
#pragma unroll
      for (int ni = 0; ni < 4; ni++)
        acc[mi][ni] = __builtin_amdgcn_mfma_f32_16x16x32_bf16(al[mi], bh[ni],
                                                              acc[mi][ni], 0, 0, 0);
    __syncthreads();
  }
  // ---- epilogue: C/D layout col=lane&15, row=(lane>>4)*4+reg ----
  if (gridDim.z == 1) {
#pragma unroll
    for (int mi = 0; mi < 4; mi++)
#pragma unroll
      for (int ni = 0; ni < 4; ni++) {
        int m = m0 + wm + mi * 16 + lg * 4;
        int sI = wn + ni * 16 + lr;
        size_t base = ((size_t)b * M + m) * S_ + sI;
#pragma unroll
        for (int r = 0; r < 4; r++) {
          float v = acc[mi][ni][r];
          if (accum) v += Out[base + (size_t)r * S_];
          Out[base + (size_t)r * S_] = v;
        }
      }
  } else {
#pragma unroll
    for (int mi = 0; mi < 4; mi++)
#pragma unroll
      for (int ni = 0; ni < 4; ni++) {
        int m = m0 + wm + mi * 16 + lg * 4;
        int sI = wn + ni * 16 + lr;
        size_t base = ((size_t)b * M + m) * S_ + sI;
#pragma unroll
        for (int r = 0; r < 4; r++)
          atomicAdd(&Out[base + (size_t)r * S_], acc[mi][ni][r]);
      }
  }
}

// ---------------- RoPE ----------------
__device__ __forceinline__ void rope_angles(int pos, int i, float& sn, float& cs) {
  float inv_freq = powf(10000.0f, -(float)i * (1.0f / 64.0f));
  float ang = (float)pos * inv_freq;
  sn = sinf(ang);
  cs = cosf(ang);
}

__global__ __launch_bounds__(256) void rope_q(float* __restrict__ q,
                                              const int* __restrict__ positions) {
  int idx = blockIdx.x * 256 + threadIdx.x;
  int s = idx & 127;
  int i = (idx >> 7) & 63;
  int b = idx >> 17;
  float sn, cs;
  rope_angles(positions[b * S_ + s], i, sn, cs);
  size_t o1 = (size_t)(idx >> 13) * (128 * S_) + (size_t)i * S_ + s;
  float x1 = q[o1], x2 = q[o1 + 64 * S_];
  q[o1] = x1 * cs - x2 * sn;
  q[o1 + 64 * S_] = x2 * cs + x1 * sn;
}

__global__ __launch_bounds__(256) void rope_k_store(const float* __restrict__ kbuf,
                                                    const int* __restrict__ positions,
                                                    const int* __restrict__ wptr,
                                                    float* __restrict__ k_cache, int l) {
  int idx = blockIdx.x * 256 + threadIdx.x;
  int i = idx & 63;
  int s = (idx >> 6) & 127;
  int kv = (idx >> 13) & 3;
  int b = idx >> 15;
  int w = wptr[0];
  float sn, cs;
  rope_angles(positions[b * S_ + s], i, sn, cs);
  size_t i1 = ((size_t)(b * HKV_ + kv) * HD_ + i) * S_ + s;
  float x1 = kbuf[i1], x2 = kbuf[i1 + 64 * S_];
  size_t o = ((size_t)((l * B_ + b) * HKV_ + kv) * A_ + (w + s)) * HD_ + i;
  k_cache[o] = x1 * cs - x2 * sn;
  k_cache[o + 64] = x2 * cs + x1 * sn;
}

__global__ __launch_bounds__(256) void store_v(const float* __restrict__ vbuf,
                                               const int* __restrict__ wptr,
                                               float* __restrict__ v_cache, int l) {
  int idx = blockIdx.x * 256 + threadIdx.x;
  int s = idx & 127;
  int hd = (idx >> 7) & 127;
  int kv = (idx >> 14) & 3;
  int b = idx >> 16;
  int w = wptr[0];
  v_cache[((size_t)((l * B_ + b) * HKV_ + kv) * HD_ + hd) * A_ + w + s] = vbuf[idx];
}

// ---------------- Attention ----------------
__global__ __launch_bounds__(256) void attn_scores(
    const float* __restrict__ key, const float* __restrict__ q, float* __restrict__ P,
    const float* __restrict__ maskArr, const int* __restrict__ encLen,
    const int* __restrict__ wptr, float scale, int gshift, int AN, int mode) {
  int bh = blockIdx.y;
  int b = bh >> 4, h = bh & 15;
  int kvh = h >> gshift;
  int nkv = 16 >> gshift;
  int a0 = blockIdx.x * 32;
  int Aeff = (mode == 0) ? (wptr[0] + S_) : T_;
  if (a0 >= Aeff) return;
  int tid = threadIdx.x;
  int s = tid & 127, ah = tid >> 7;
  __shared__ float qs[32][128];
  __shared__ float ks[32][32];
  float acc[16];
#pragma unroll
  for (int j = 0; j < 16; j++) acc[j] = 0.f;
  const float* kbase = key + (size_t)(b * nkv + kvh) * AN * HD_;
  const float* qbase = q + (size_t)bh * HD_ * S_;
  for (int hc = 0; hc < HD_; hc += 32) {
    for (int i = tid; i < 32 * 128; i += 256) {
      int c = i >> 7, ss = i & 127;
      qs[c][ss] = qbase[(size_t)(hc + c) * S_ + ss];
    }
    for (int i = tid; i < 32 * 32; i += 256) {
      int aj = i >> 5, c = i & 31;
      int a = a0 + aj;
      ks[aj][c] = (a < Aeff) ? kbase[(size_t)a * HD_ + hc + c] : 0.f;
    }
    __syncthreads();
#pragma unroll
    for (int j = 0; j < 16; j++) {
      int aj = ah + 2 * j;
      float sum = 0.f;
#pragma unroll
      for (int c = 0; c < 32; c++) sum += ks[aj][c] * qs[c][s];
      acc[j] += sum;
    }
    __syncthreads();
  }
  for (int j = 0; j < 16; j++) {
    int a = a0 + ah + 2 * j;
    if (a < Aeff) {
      float mval;
      if (mode == 0)
        mval = maskArr[((size_t)b * S_ + s) * A_ + a];
      else
        mval = (a < encLen[b]) ? 0.f : NEG_;
      P[((size_t)bh * S_ + s) * T_ + a] = acc[j] * scale + mval;
    }
  }
}

__global__ __launch_bounds__(128) void softmax_rows(float* __restrict__ P,
                                                    const int* __restrict__ wptr,
                                                    int mode) {
  int row = blockIdx.x;
  int Aeff = (mode == 0) ? (wptr[0] + S_) : T_;
  float* p = P + (size_t)row * T_;
  int tid = threadIdx.x;
  float v[4];
  int cnt = 0;
  float m = -1e30f;
  for (int a = tid; a < Aeff; a += 128) {
    float t = p[a];
    v[cnt++] = t;
    m = fmaxf(m, t);
  }
  __shared__ float r0[2], r1[2];
  for (int off = 32; off > 0; off >>= 1) m = fmaxf(m, __shfl_down(m, off));
  if ((tid & 63) == 0) r0[tid >> 6] = m;
  __syncthreads();
  m = fmaxf(r0[0], r0[1]);
  float sum = 0.f;
  for (int i = 0; i < cnt; i++) {
    v[i] = expf(v[i] - m);
    sum += v[i];
  }
  for (int off = 32; off > 0; off >>= 1) sum += __shfl_down(sum, off);
  if ((tid & 63) == 0) r1[tid >> 6] = sum;
  __syncthreads();
  float inv = 1.f / (r1[0] + r1[1]);
  cnt = 0;
  for (int a = tid; a < Aeff; a += 128) p[a] = v[cnt++] * inv;
}

__global__ __launch_bounds__(256) void attn_pv(const float* __restrict__ val,
                                               const float* __restrict__ P,
                                               float* __restrict__ out,
                                               const int* __restrict__ wptr, int gshift,
                                               int AN, int mode) {
  int bh = blockIdx.y;
  int b = bh >> 4, h = bh & 15;
  int kvh = h >> gshift, nkv = 16 >> gshift;
  int hd0 = blockIdx.x * 32;
  int Aeff = (mode == 0) ? (wptr[0] + S_) : T_;
  int tid = threadIdx.x;
  int s = tid & 127, hh = tid >> 7;
  __shared__ float ps[32][128];
  __shared__ float vs[32][32];
  float acc[16];
#pragma unroll
  for (int j = 0; j < 16; j++) acc[j] = 0.f;
  const float* vbase = val + (size_t)(b * nkv + kvh) * HD_ * AN;
  const float* Pb = P + (size_t)bh * S_ * T_;
  for (int a0 = 0; a0 < Aeff; a0 += 32) {
    for (int i = tid; i < 32 * 128; i += 256) {
      int ss = i >> 5, aj = i & 31;
      int a = a0 + aj;
      ps[aj][ss] = (a < Aeff) ? Pb[(size_t)ss * T_ + a] : 0.f;
    }
    for (int i = tid; i < 32 * 32; i += 256) {
      int c = i >> 5, aj = i & 31;
      vs[c][aj] = vbase[(size_t)(hd0 + c) * AN + a0 + aj];
    }
    __syncthreads();
#pragma unroll
    for (int j = 0; j < 16; j++) {
      int c = hh + 2 * j;
      float sum = 0.f;
#pragma unroll
      for (int aj = 0; aj < 32; aj++) sum += vs[c][aj] * ps[aj][s];
      acc[j] += sum;
    }
    __syncthreads();
  }
#pragma unroll
  for (int j = 0; j < 16; j++) {
    int hd = hd0 + hh + 2 * j;
    out[((size_t)bh * HD_ + hd) * S_ + s] = acc[j];
  }
}

__global__ __launch_bounds__(256) void silu_mul(float* __restrict__ gate,
                                                const float* __restrict__ up) {
  int i = blockIdx.x * 256 + threadIdx.x;
  float g = gate[i];
  gate[i] = g / (1.f + expf(-g)) * up[i];
}

}  // namespace

extern "C" void kernel_launch(void* const* d_in, const int* in_sizes, int n_in,
                              void* d_out, int out_size, void* d_ws, size_t ws_size,
                              hipStream_t stream) {
  const float* x_in = (const float*)d_in[0];
  const int* positions = (const int*)d_in[1];
  const int* wptr = (const int*)d_in[2];
  const float* maskArr = (const float*)d_in[3];
  const int* encLen = (const int*)d_in[4];
  const float* q_w = (const float*)d_in[5];
  const float* k_w = (const float*)d_in[6];
  const float* v_w = (const float*)d_in[7];
  const float* o_w = (const float*)d_in[8];
  const float* cq_w = (const float*)d_in[9];
  const float* co_w = (const float*)d_in[10];
  const float* sa_norm = (const float*)d_in[11];
  const float* ca_norm = (const float*)d_in[12];
  const float* mlp_norm = (const float*)d_in[13];
  const float* fin_norm = (const float*)d_in[14];
  const float* wg_w = (const float*)d_in[15];
  const float* wu_w = (const float*)d_in[16];
  const float* wd_w = (const float*)d_in[17];
  float* k_cache = (float*)d_in[18];
  float* v_cache = (float*)d_in[19];
  const float* ck_cache = (const float*)d_in[20];
  const float* cv_cache = (const float*)d_in[21];
  float* out = (float*)d_out;

  float* ws = (float*)d_ws;
  const size_t BDS = (size_t)B_ * D_ * S_;        // 524288
  float* X = ws;                                   // (B,D,S)
  float* Hb = X + BDS;                             // normalized activations
  float* Q = Hb + BDS;                             // q / cq (B,2048,S)
  float* Attn = Q + BDS;                           // attention output (B,2048,S)
  float* Kb = Attn + BDS;                          // (B,512,S)
  float* Vb = Kb + (size_t)B_ * 512 * S_;          // (B,512,S)
  float* Pbuf = Vb + (size_t)B_ * 512 * S_;        // scores (B*16,S,512) / gate (B,FF,S)
  float* Up = Pbuf + (size_t)B_ * 16 * S_ * T_;    // up (B,FF,S)
  float* Rsum = Up + (size_t)B_ * FF_ * S_;        // (B,S)
  uint32_t* Ht = (uint32_t*)(Rsum + B_ * S_);      // packed activations (256, K<=8192)

  const float scale = 0.08838834764831845f;  // 1/sqrt(128), HD == HDC

  hipMemcpyAsync(X, x_in, BDS * sizeof(float), hipMemcpyDeviceToDevice, stream);

  auto rms = [&](const float* src, const float* w, float* dst) {
    hipMemsetAsync(Rsum, 0, B_ * S_ * sizeof(float), stream);
    rms_sumsq<<<dim3(16, B_), 256, 0, stream>>>(src, Rsum);
    rms_apply<<<dim3(B_ * D_ * S_ / 256), 256, 0, stream>>>(src, Rsum, w, dst);
  };
  auto pack = [&](const float* src, int K) {
    pack_h<<<dim3(K / 64, B_), 256, 0, stream>>>(src, Ht, K);
  };
  // zero=1: fresh output (memset then atomic split-K add)
  // accum=1: add into existing Out (residual) via atomics
  auto mgemm = [&](const float* Wm, float* Outm, int M, int K, int SK, int accum,
                   int zero) {
    if (zero)
      hipMemsetAsync(Outm, 0, (size_t)B_ * M * S_ * sizeof(float), stream);
    gemm_mfma<<<dim3(M / 128, B_, SK), 256, 0, stream>>>(Wm, Ht, Outm, M, K, K / SK,
                                                         accum);
  };

  for (int l = 0; l < L_; l++) {
    // ---- self attention ----
    rms(X, sa_norm + (size_t)l * D_, Hb);
    pack(Hb, D_);
    mgemm(q_w + (size_t)l * D_ * 2048, Q, 2048, D_, 4, 0, 1);
    mgemm(k_w + (size_t)l * D_ * 512, Kb, 512, D_, 8, 0, 1);
    mgemm(v_w + (size_t)l * D_ * 512, Vb, 512, D_, 8, 0, 1);
    rope_q<<<dim3(B_ * 16 * 64 * S_ / 256), 256, 0, stream>>>(Q, positions);
    rope_k_store<<<dim3(B_ * 4 * S_ * 64 / 256), 256, 0, stream>>>(Kb, positions, wptr,
                                                                   k_cache, l);
    store_v<<<dim3(B_ * 4 * 128 * S_ / 256), 256, 0, stream>>>(Vb, wptr, v_cache, l);
    attn_scores<<<dim3(16, 32), 256, 0, stream>>>(
        k_cache + (size_t)l * B_ * HKV_ * A_ * HD_, Q, Pbuf, maskArr, encLen, wptr,
        scale, 2, A_, 0);
    softmax_rows<<<dim3(B_ * 16 * S_), 128, 0, stream>>>(Pbuf, wptr, 0);
    attn_pv<<<dim3(4, 32), 256, 0, stream>>>(
        v_cache + (size_t)l * B_ * HKV_ * HD_ * A_, Pbuf, Attn, wptr, 2, A_, 0);
    pack(Attn, D_);
    mgemm(o_w + (size_t)l * 2048 * D_, X, D_, 2048, 4, 1, 0);
    // ---- cross attention ----
    rms(X, ca_norm + (size_t)l * D_, Hb);
    pack(Hb, D_);
    mgemm(cq_w + (size_t)l * D_ * 2048, Q, 2048, D_, 4, 0, 1);
    rope_q<<<dim3(B_ * 16 * 64 * S_ / 256), 256, 0, stream>>>(Q, positions);
    attn_scores<<<dim3(16, 32), 256, 0, stream>>>(
        ck_cache + (size_t)l * B_ * 16 * T_ * HD_, Q, Pbuf, maskArr, encLen, wptr,
        scale, 0, T_, 1);
    softmax_rows<<<dim3(B_ * 16 * S_), 128, 0, stream>>>(Pbuf, wptr, 1);
    attn_pv<<<dim3(4, 32), 256, 0, stream>>>(
        cv_cache + (size_t)l * B_ * 16 * HD_ * T_, Pbuf, Attn, wptr, 0, T_, 1);
    pack(Attn, D_);
    mgemm(co_w + (size_t)l * 2048 * D_, X, D_, 2048, 4, 1, 0);
    // ---- MLP ----
    rms(X, mlp_norm + (size_t)l * D_, Hb);
    pack(Hb, D_);
    mgemm(wg_w + (size_t)l * D_ * FF_, Pbuf, FF_, D_, 2, 0, 1);
    mgemm(wu_w + (size_t)l * D_ * FF_, Up, FF_, D_, 2, 0, 1);
    silu_mul<<<dim3(B_ * FF_ * S_ / 256), 256, 0, stream>>>(Pbuf, Up);
    pack(Pbuf, FF_);
    mgemm(wd_w + (size_t)l * FF_ * D_, X, D_, FF_, 8, 1, 0);
  }
  // ---- final norm -> d_out ----
  rms(X, fin_norm, out);
}

// Round 4
// 1818.897 us; speedup vs baseline: 1.2107x; 1.2107x over previous
//
#include <hip/hip_runtime.h>
#include <math.h>
#include <stdint.h>

namespace {

constexpr int B_ = 2, D_ = 2048, S_ = 128, A_ = 1536, T_ = 512;
constexpr int HQ_ = 16, HKV_ = 4, HD_ = 128, FF_ = 8192, L_ = 2;
constexpr float NEG_ = -30000.0f, EPS_ = 1e-5f;
constexpr int TOK_ = B_ * S_;  // 256 tokens

typedef __attribute__((ext_vector_type(4))) float f32x4;
typedef __attribute__((ext_vector_type(8))) short s16x8;  // 8 bf16 (4 VGPRs)

// split fp32 -> (hi bf16, lo bf16) packed in one u32: low16=hi, high16=lo.
__device__ __forceinline__ uint32_t bf16pair(float x) {
  uint32_t xi = __float_as_uint(x);
  uint32_t hi = (xi + 0x7FFFu + ((xi >> 16) & 1u)) >> 16;
  float hf = __uint_as_float(hi << 16);
  float r = x - hf;  // exact
  uint32_t ri = __float_as_uint(r);
  uint32_t lo = (ri + 0x7FFFu + ((ri >> 16) & 1u)) >> 16;
  return (hi & 0xFFFFu) | (lo << 16);
}

// unpack 8 interleaved u32 {hi,lo} -> hi-fragment and lo-fragment (bf16x8)
__device__ __forceinline__ void unpack8(uint4 q0, uint4 q1, s16x8& hi, s16x8& lo) {
  union U { uint32_t w[4]; s16x8 v; };
  U h, l;
  uint32_t u[8] = {q0.x, q0.y, q0.z, q0.w, q1.x, q1.y, q1.z, q1.w};
#pragma unroll
  for (int r = 0; r < 4; r++) {
    h.w[r] = __builtin_amdgcn_perm(u[2 * r + 1], u[2 * r], 0x05040100u);
    l.w[r] = __builtin_amdgcn_perm(u[2 * r + 1], u[2 * r], 0x07060302u);
  }
  hi = h.v;
  lo = l.v;
}

// ---------------- RMSNorm ----------------
__global__ __launch_bounds__(256) void rms_sumsq(const float* __restrict__ x,
                                                 float* __restrict__ rsum) {
  int b = blockIdx.y, c = blockIdx.x;
  int tid = threadIdx.x;
  int s = tid & 127, dd = tid >> 7;
  const float* xp = x + ((size_t)b * D_ + c * 128) * S_ + s;
  float acc = 0.f;
  for (int d = dd; d < 128; d += 2) {
    float v = xp[(size_t)d * S_];
    acc += v * v;
  }
  __shared__ float lds[256];
  lds[tid] = acc;
  __syncthreads();
  if (dd == 0) atomicAdd(&rsum[b * S_ + s], lds[s] + lds[128 + s]);
}

__global__ __launch_bounds__(256) void rms_apply(const float* __restrict__ x,
                                                 const float* __restrict__ rsum,
                                                 const float* __restrict__ w,
                                                 float* __restrict__ out) {
  int i = blockIdx.x * 256 + threadIdx.x;
  int s = i & (S_ - 1);
  int d = (i / S_) & (D_ - 1);
  int b = i / (D_ * S_);
  float inv = rsqrtf(rsum[b * S_ + s] * (1.0f / D_) + EPS_);
  out[i] = x[i] * inv * w[d];
}

// ---------------- pack H: [b][K][S] fp32 -> Ht[b*128+s][K] u32{hi,lo} -------
__global__ __launch_bounds__(256) void pack_h(const float* __restrict__ H,
                                              uint32_t* __restrict__ Ht, int K) {
  int b = blockIdx.y;
  int k0 = blockIdx.x * 64;
  __shared__ uint32_t t[128][65];
  int tid = threadIdx.x;
  int s = tid & 127, kk = tid >> 7;
  const float* Hp = H + ((size_t)b * K + k0) * S_ + s;
  for (int k = kk; k < 64; k += 2) t[s][k] = bf16pair(Hp[(size_t)k * S_]);
  __syncthreads();
  int k2 = tid & 63, s2 = tid >> 6;
  uint32_t* Op = Ht + (size_t)(b * S_) * K + k0 + k2;
  for (int ss = s2; ss < 128; ss += 4) Op[(size_t)ss * K] = t[ss][k2];
}

// ---------------- split-bf16 MFMA GEMM ----------------
// C[b, m, s] (+)= sum_k W[k*M + m] * H[b, k, s]
__global__ __launch_bounds__(256, 2) void gemm_mfma(
    const float* __restrict__ W, const uint32_t* __restrict__ Ht,
    float* __restrict__ Out, int M, int K, int KC, int accum) {
  __shared__ uint32_t As[128 * 32];
  __shared__ uint32_t Bs[128 * 32];
  int m0 = blockIdx.x * 128;
  int b = blockIdx.y;
  int k0 = blockIdx.z * KC;
  int tid = threadIdx.x;
  int lane = tid & 63, wave = tid >> 6;
  int wm = (wave >> 1) * 64, wn = (wave & 1) * 64;
  int lr = lane & 15, lg = lane >> 4;
  int a_k4 = (tid >> 5) * 4;
  int a_m4 = (tid & 31) * 4;
  int ag = a_k4 >> 2;
  int b_g = tid & 3;
  int b_s = tid >> 2;
  const uint32_t* HtB = Ht + (size_t)(b * S_) * K;

  f32x4 acc[4][4];
  f32x4 zero = {0.f, 0.f, 0.f, 0.f};
#pragma unroll
  for (int i = 0; i < 4; i++)
#pragma unroll
    for (int j = 0; j < 4; j++) acc[i][j] = zero;

  for (int kk = k0; kk < k0 + KC; kk += 32) {
    const float* Wp = W + (size_t)(kk + a_k4) * M + (m0 + a_m4);
    float4 w0 = *(const float4*)(Wp);
    float4 w1 = *(const float4*)(Wp + (size_t)M);
    float4 w2 = *(const float4*)(Wp + 2 * (size_t)M);
    float4 w3 = *(const float4*)(Wp + 3 * (size_t)M);
    {
      uint4 u;
      int m = a_m4;
      u.x = bf16pair(w0.x); u.y = bf16pair(w1.x); u.z = bf16pair(w2.x); u.w = bf16pair(w3.x);
      *(uint4*)&As[m * 32 + ((ag ^ (m & 7)) << 2)] = u;
      m = a_m4 + 1;
      u.x = bf16pair(w0.y); u.y = bf16pair(w1.y); u.z = bf16pair(w2.y); u.w = bf16pair(w3.y);
      *(uint4*)&As[m * 32 + ((ag ^ (m & 7)) << 2)] = u;
      m = a_m4 + 2;
      u.x = bf16pair(w0.z); u.y = bf16pair(w1.z); u.z = bf16pair(w2.z); u.w = bf16pair(w3.z);
      *(uint4*)&As[m * 32 + ((ag ^ (m & 7)) << 2)] = u;
      m = a_m4 + 3;
      u.x = bf16pair(w0.w); u.y = bf16pair(w1.w); u.z = bf16pair(w2.w); u.w = bf16pair(w3.w);
      *(uint4*)&As[m * 32 + ((ag ^ (m & 7)) << 2)] = u;
    }
#pragma unroll
    for (int c = 0; c < 2; c++)
#pragma unroll
      for (int d = 0; d < 2; d++) {
        int s = b_s + c * 64;
        int g = b_g + d * 4;
        uint4 v = *(const uint4*)&HtB[(size_t)s * K + kk + g * 4];
        *(uint4*)&Bs[s * 32 + ((g ^ (s & 7)) << 2)] = v;
      }
    __syncthreads();
    s16x8 ah[4], al[4], bhf[4], blf[4];
#pragma unroll
    for (int mi = 0; mi < 4; mi++) {
      int row = wm + mi * 16 + lr;
      const uint32_t* p = &As[row * 32];
      uint4 q0 = *(const uint4*)&p[(((lg << 1) ^ (row & 7)) << 2)];
      uint4 q1 = *(const uint4*)&p[((((lg << 1) | 1) ^ (row & 7)) << 2)];
      unpack8(q0, q1, ah[mi], al[mi]);
    }
#pragma unroll
    for (int ni = 0; ni < 4; ni++) {
      int row = wn + ni * 16 + lr;
      const uint32_t* p = &Bs[row * 32];
      uint4 q0 = *(const uint4*)&p[(((lg << 1) ^ (row & 7)) << 2)];
      uint4 q1 = *(const uint4*)&p[((((lg << 1) | 1) ^ (row & 7)) << 2)];
      unpack8(q0, q1, bhf[ni], blf[ni]);
    }
#pragma unroll
    for (int mi = 0; mi < 4; mi++)
#pragma unroll
      for (int ni = 0; ni < 4; ni++)
        acc[mi][ni] = __builtin_amdgcn_mfma_f32_16x16x32_bf16(ah[mi], bhf[ni],
                                                              acc[mi][ni], 0, 0, 0);
#pragma unroll
    for (int mi = 0; mi < 4; mi++)
#pragma unroll
      for (int ni = 0; ni < 4; ni++)
        acc[mi][ni] = __builtin_amdgcn_mfma_f32_16x16x32_bf16(ah[mi], blf[ni],
                                                              acc[mi][ni], 0, 0, 0);
#pragma unroll
    for (int mi = 0; mi < 4; mi++)
#pragma unroll
      for (int ni = 0; ni < 4; ni++)
        acc[mi][ni] = __builtin_amdgcn_mfma_f32_16x16x32_bf16(al[mi], bhf[ni],
                                                              acc[mi][ni], 0, 0, 0);
    __syncthreads();
  }
  if (gridDim.z == 1) {
#pragma unroll
    for (int mi = 0; mi < 4; mi++)
#pragma unroll
      for (int ni = 0; ni < 4; ni++) {
        int m = m0 + wm + mi * 16 + lg * 4;
        int sI = wn + ni * 16 + lr;
        size_t base = ((size_t)b * M + m) * S_ + sI;
#pragma unroll
        for (int r = 0; r < 4; r++) {
          float v = acc[mi][ni][r];
          if (accum) v += Out[base + (size_t)r * S_];
          Out[base + (size_t)r * S_] = v;
        }
      }
  } else {
#pragma unroll
    for (int mi = 0; mi < 4; mi++)
#pragma unroll
      for (int ni = 0; ni < 4; ni++) {
        int m = m0 + wm + mi * 16 + lg * 4;
        int sI = wn + ni * 16 + lr;
        size_t base = ((size_t)b * M + m) * S_ + sI;
#pragma unroll
        for (int r = 0; r < 4; r++)
          atomicAdd(&Out[base + (size_t)r * S_], acc[mi][ni][r]);
      }
  }
}

// ---------------- MFMA attention scores ----------------
// P[bh, s, a] = scale * sum_hd K[a,hd]*Qt[s,h*128+hd] + mask
// M-dim = a (rows), N-dim = s. A-operand = K cache (hd-contiguous, fp32->pair),
// B-operand = packed Qt (hd-contiguous u32). grid (4, B*16), 256 thr.
__global__ __launch_bounds__(256, 2) void attn_scores_mfma(
    const float* __restrict__ key, const uint32_t* __restrict__ Qt,
    float* __restrict__ P, const float* __restrict__ maskArr,
    const int* __restrict__ encLen, const int* __restrict__ wptr, float scale,
    int gshift, int AN, int mode) {
  int bh = blockIdx.y;
  int b = bh >> 4, h = bh & 15;
  int kvh = h >> gshift, nkv = 16 >> gshift;
  int Aeff = (mode == 0) ? (wptr[0] + S_) : T_;
  int a0 = blockIdx.x * 128;
  if (a0 >= Aeff) return;
  __shared__ uint32_t As[128 * 32];  // rows = a
  __shared__ uint32_t Bs[128 * 32];  // rows = s
  const float* kbase =
      key + (size_t)(b * nkv + kvh) * AN * HD_ + (size_t)a0 * HD_;
  const uint32_t* qbase = Qt + (size_t)(b * S_) * D_ + h * HD_;  // row stride D_
  int tid = threadIdx.x, lane = tid & 63, wave = tid >> 6;
  int wm = (wave >> 1) * 64, wn = (wave & 1) * 64;
  int lr = lane & 15, lg = lane >> 4;
  int g_ = tid & 3, r_ = tid >> 2;

  f32x4 acc[4][4];
  f32x4 zero = {0.f, 0.f, 0.f, 0.f};
#pragma unroll
  for (int i = 0; i < 4; i++)
#pragma unroll
    for (int j = 0; j < 4; j++) acc[i][j] = zero;

  for (int hc = 0; hc < HD_; hc += 32) {
#pragma unroll
    for (int c = 0; c < 2; c++)
#pragma unroll
      for (int d = 0; d < 2; d++) {
        int row = r_ + c * 64, g = g_ + d * 4;
        float4 v = *(const float4*)&kbase[(size_t)row * HD_ + hc + g * 4];
        uint4 u;
        u.x = bf16pair(v.x); u.y = bf16pair(v.y);
        u.z = bf16pair(v.z); u.w = bf16pair(v.w);
        *(uint4*)&As[row * 32 + ((g ^ (row & 7)) << 2)] = u;
        uint4 q = *(const uint4*)&qbase[(size_t)row * D_ + hc + g * 4];
        *(uint4*)&Bs[row * 32 + ((g ^ (row & 7)) << 2)] = q;
      }
    __syncthreads();
    s16x8 ah[4], al[4], bhf[4], blf[4];
#pragma unroll
    for (int mi = 0; mi < 4; mi++) {
      int row = wm + mi * 16 + lr;
      const uint32_t* p = &As[row * 32];
      uint4 q0 = *(const uint4*)&p[(((lg << 1) ^ (row & 7)) << 2)];
      uint4 q1 = *(const uint4*)&p[((((lg << 1) | 1) ^ (row & 7)) << 2)];
      unpack8(q0, q1, ah[mi], al[mi]);
    }
#pragma unroll
    for (int ni = 0; ni < 4; ni++) {
      int row = wn + ni * 16 + lr;
      const uint32_t* p = &Bs[row * 32];
      uint4 q0 = *(const uint4*)&p[(((lg << 1) ^ (row & 7)) << 2)];
      uint4 q1 = *(const uint4*)&p[((((lg << 1) | 1) ^ (row & 7)) << 2)];
      unpack8(q0, q1, bhf[ni], blf[ni]);
    }
#pragma unroll
    for (int mi = 0; mi < 4; mi++)
#pragma unroll
      for (int ni = 0; ni < 4; ni++)
        acc[mi][ni] = __builtin_amdgcn_mfma_f32_16x16x32_bf16(ah[mi], bhf[ni],
                                                              acc[mi][ni], 0, 0, 0);
#pragma unroll
    for (int mi = 0; mi < 4; mi++)
#pragma unroll
      for (int ni = 0; ni < 4; ni++)
        acc[mi][ni] = __builtin_amdgcn_mfma_f32_16x16x32_bf16(ah[mi], blf[ni],
                                                              acc[mi][ni], 0, 0, 0);
#pragma unroll
    for (int mi = 0; mi < 4; mi++)
#pragma unroll
      for (int ni = 0; ni < 4; ni++)
        acc[mi][ni] = __builtin_amdgcn_mfma_f32_16x16x32_bf16(al[mi], bhf[ni],
                                                              acc[mi][ni], 0, 0, 0);
    __syncthreads();
  }
  // epilogue: row = a (m-dim), col = s; fuse scale + mask
  int eLen = (mode == 0) ? 0 : encLen[b];
#pragma unroll
  for (int mi = 0; mi < 4; mi++)
#pragma unroll
    for (int ni = 0; ni < 4; ni++) {
      int ab = a0 + wm + mi * 16 + lg * 4;
      int s = wn + ni * 16 + lr;
      float* Pp = P + ((size_t)bh * S_ + s) * T_;
      const float* Mp = maskArr + ((size_t)b * S_ + s) * A_;
#pragma unroll
      for (int r = 0; r < 4; r++) {
        int a = ab + r;
        if (a < Aeff) {
          float mval = (mode == 0) ? Mp[a] : ((a < eLen) ? 0.f : NEG_);
          Pp[a] = acc[mi][ni][r] * scale + mval;
        }
      }
    }
}

// ---------------- MFMA attention PV ----------------
// out[bh*128+hd, s] = sum_a V[hd,a] * P[s,a]^T. Both operands a-contiguous.
// grid (B*16), 256 thr. P zero-padded past Aeff at staging.
__global__ __launch_bounds__(256, 2) void attn_pv_mfma(
    const float* __restrict__ val, const float* __restrict__ P,
    float* __restrict__ out, const int* __restrict__ wptr, int gshift, int AN,
    int mode) {
  int bh = blockIdx.x;
  int b = bh >> 4, h = bh & 15;
  int kvh = h >> gshift, nkv = 16 >> gshift;
  int Aeff = (mode == 0) ? (wptr[0] + S_) : T_;
  int nk = (Aeff + 31) >> 5;
  __shared__ uint32_t As[128 * 32];  // rows = hd
  __shared__ uint32_t Bs[128 * 32];  // rows = s
  const float* vbase = val + (size_t)(b * nkv + kvh) * HD_ * AN;
  const float* Pb = P + (size_t)bh * S_ * T_;
  int tid = threadIdx.x, lane = tid & 63, wave = tid >> 6;
  int wm = (wave >> 1) * 64, wn = (wave & 1) * 64;
  int lr = lane & 15, lg = lane >> 4;
  int g_ = tid & 3, r_ = tid >> 2;

  f32x4 acc[4][4];
  f32x4 zero = {0.f, 0.f, 0.f, 0.f};
#pragma unroll
  for (int i = 0; i < 4; i++)
#pragma unroll
    for (int j = 0; j < 4; j++) acc[i][j] = zero;

  for (int kkt = 0; kkt < nk; kkt++) {
    int a0c = kkt * 32;
#pragma unroll
    for (int c = 0; c < 2; c++)
#pragma unroll
      for (int d = 0; d < 2; d++) {
        int row = r_ + c * 64, g = g_ + d * 4;
        int a = a0c + g * 4;
        float4 v = *(const float4*)&vbase[(size_t)row * AN + a];
        uint4 u;
        u.x = bf16pair(v.x); u.y = bf16pair(v.y);
        u.z = bf16pair(v.z); u.w = bf16pair(v.w);
        *(uint4*)&As[row * 32 + ((g ^ (row & 7)) << 2)] = u;
        float4 p4 = *(const float4*)&Pb[(size_t)row * T_ + a];
        uint4 up;
        up.x = (a + 0 < Aeff) ? bf16pair(p4.x) : 0u;
        up.y = (a + 1 < Aeff) ? bf16pair(p4.y) : 0u;
        up.z = (a + 2 < Aeff) ? bf16pair(p4.z) : 0u;
        up.w = (a + 3 < Aeff) ? bf16pair(p4.w) : 0u;
        *(uint4*)&Bs[row * 32 + ((g ^ (row & 7)) << 2)] = up;
      }
    __syncthreads();
    s16x8 ah[4], al[4], bhf[4], blf[4];
#pragma unroll
    for (int mi = 0; mi < 4; mi++) {
      int row = wm + mi * 16 + lr;
      const uint32_t* p = &As[row * 32];
      uint4 q0 = *(const uint4*)&p[(((lg << 1) ^ (row & 7)) << 2)];
      uint4 q1 = *(const uint4*)&p[((((lg << 1) | 1) ^ (row & 7)) << 2)];
      unpack8(q0, q1, ah[mi], al[mi]);
    }
#pragma unroll
    for (int ni = 0; ni < 4; ni++) {
      int row = wn + ni * 16 + lr;
      const uint32_t* p = &Bs[row * 32];
      uint4 q0 = *(const uint4*)&p[(((lg << 1) ^ (row & 7)) << 2)];
      uint4 q1 = *(const uint4*)&p[((((lg << 1) | 1) ^ (row & 7)) << 2)];
      unpack8(q0, q1, bhf[ni], blf[ni]);
    }
#pragma unroll
    for (int mi = 0; mi < 4; mi++)
#pragma unroll
      for (int ni = 0; ni < 4; ni++)
        acc[mi][ni] = __builtin_amdgcn_mfma_f32_16x16x32_bf16(ah[mi], bhf[ni],
                                                              acc[mi][ni], 0, 0, 0);
#pragma unroll
    for (int mi = 0; mi < 4; mi++)
#pragma unroll
      for (int ni = 0; ni < 4; ni++)
        acc[mi][ni] = __builtin_amdgcn_mfma_f32_16x16x32_bf16(ah[mi], blf[ni],
                                                              acc[mi][ni], 0, 0, 0);
#pragma unroll
    for (int mi = 0; mi < 4; mi++)
#pragma unroll
      for (int ni = 0; ni < 4; ni++)
        acc[mi][ni] = __builtin_amdgcn_mfma_f32_16x16x32_bf16(al[mi], bhf[ni],
                                                              acc[mi][ni], 0, 0, 0);
    __syncthreads();
  }
  // epilogue: row = hd, col = s
#pragma unroll
  for (int mi = 0; mi < 4; mi++)
#pragma unroll
    for (int ni = 0; ni < 4; ni++) {
      int hd = wm + mi * 16 + lg * 4;
      int s = wn + ni * 16 + lr;
      size_t base = ((size_t)bh * HD_ + hd) * S_ + s;
#pragma unroll
      for (int r = 0; r < 4; r++) out[base + (size_t)r * S_] = acc[mi][ni][r];
    }
}

// ---------------- RoPE ----------------
__device__ __forceinline__ void rope_angles(int pos, int i, float& sn, float& cs) {
  float inv_freq = powf(10000.0f, -(float)i * (1.0f / 64.0f));
  float ang = (float)pos * inv_freq;
  sn = sinf(ang);
  cs = cosf(ang);
}

__global__ __launch_bounds__(256) void rope_q(float* __restrict__ q,
                                              const int* __restrict__ positions) {
  int idx = blockIdx.x * 256 + threadIdx.x;
  int s = idx & 127;
  int i = (idx >> 7) & 63;
  int b = idx >> 17;
  float sn, cs;
  rope_angles(positions[b * S_ + s], i, sn, cs);
  size_t o1 = (size_t)(idx >> 13) * (128 * S_) + (size_t)i * S_ + s;
  float x1 = q[o1], x2 = q[o1 + 64 * S_];
  q[o1] = x1 * cs - x2 * sn;
  q[o1 + 64 * S_] = x2 * cs + x1 * sn;
}

__global__ __launch_bounds__(256) void rope_k_store(const float* __restrict__ kbuf,
                                                    const int* __restrict__ positions,
                                                    const int* __restrict__ wptr,
                                                    float* __restrict__ k_cache, int l) {
  int idx = blockIdx.x * 256 + threadIdx.x;
  int i = idx & 63;
  int s = (idx >> 6) & 127;
  int kv = (idx >> 13) & 3;
  int b = idx >> 15;
  int w = wptr[0];
  float sn, cs;
  rope_angles(positions[b * S_ + s], i, sn, cs);
  size_t i1 = ((size_t)(b * HKV_ + kv) * HD_ + i) * S_ + s;
  float x1 = kbuf[i1], x2 = kbuf[i1 + 64 * S_];
  size_t o = ((size_t)((l * B_ + b) * HKV_ + kv) * A_ + (w + s)) * HD_ + i;
  k_cache[o] = x1 * cs - x2 * sn;
  k_cache[o + 64] = x2 * cs + x1 * sn;
}

__global__ __launch_bounds__(256) void store_v(const float* __restrict__ vbuf,
                                               const int* __restrict__ wptr,
                                               float* __restrict__ v_cache, int l) {
  int idx = blockIdx.x * 256 + threadIdx.x;
  int s = idx & 127;
  int hd = (idx >> 7) & 127;
  int kv = (idx >> 14) & 3;
  int b = idx >> 16;
  int w = wptr[0];
  v_cache[((size_t)((l * B_ + b) * HKV_ + kv) * HD_ + hd) * A_ + w + s] = vbuf[idx];
}

// ---------------- softmax ----------------
__global__ __launch_bounds__(128) void softmax_rows(float* __restrict__ P,
                                                    const int* __restrict__ wptr,
                                                    int mode) {
  int row = blockIdx.x;
  int Aeff = (mode == 0) ? (wptr[0] + S_) : T_;
  float* p = P + (size_t)row * T_;
  int tid = threadIdx.x;
  float v[4];
  int cnt = 0;
  float m = -1e30f;
  for (int a = tid; a < Aeff; a += 128) {
    float t = p[a];
    v[cnt++] = t;
    m = fmaxf(m, t);
  }
  __shared__ float r0[2], r1[2];
  for (int off = 32; off > 0; off >>= 1) m = fmaxf(m, __shfl_down(m, off));
  if ((tid & 63) == 0) r0[tid >> 6] = m;
  __syncthreads();
  m = fmaxf(r0[0], r0[1]);
  float sum = 0.f;
  for (int i = 0; i < cnt; i++) {
    v[i] = expf(v[i] - m);
    sum += v[i];
  }
  for (int off = 32; off > 0; off >>= 1) sum += __shfl_down(sum, off);
  if ((tid & 63) == 0) r1[tid >> 6] = sum;
  __syncthreads();
  float inv = 1.f / (r1[0] + r1[1]);
  cnt = 0;
  for (int a = tid; a < Aeff; a += 128) p[a] = v[cnt++] * inv;
}

__global__ __launch_bounds__(256) void silu_mul(float* __restrict__ gate,
                                                const float* __restrict__ up) {
  int i = blockIdx.x * 256 + threadIdx.x;
  float g = gate[i];
  gate[i] = g / (1.f + expf(-g)) * up[i];
}

}  // namespace

extern "C" void kernel_launch(void* const* d_in, const int* in_sizes, int n_in,
                              void* d_out, int out_size, void* d_ws, size_t ws_size,
                              hipStream_t stream) {
  const float* x_in = (const float*)d_in[0];
  const int* positions = (const int*)d_in[1];
  const int* wptr = (const int*)d_in[2];
  const float* maskArr = (const float*)d_in[3];
  const int* encLen = (const int*)d_in[4];
  const float* q_w = (const float*)d_in[5];
  const float* k_w = (const float*)d_in[6];
  const float* v_w = (const float*)d_in[7];
  const float* o_w = (const float*)d_in[8];
  const float* cq_w = (const float*)d_in[9];
  const float* co_w = (const float*)d_in[10];
  const float* sa_norm = (const float*)d_in[11];
  const float* ca_norm = (const float*)d_in[12];
  const float* mlp_norm = (const float*)d_in[13];
  const float* fin_norm = (const float*)d_in[14];
  const float* wg_w = (const float*)d_in[15];
  const float* wu_w = (const float*)d_in[16];
  const float* wd_w = (const float*)d_in[17];
  float* k_cache = (float*)d_in[18];
  float* v_cache = (float*)d_in[19];
  const float* ck_cache = (const float*)d_in[20];
  const float* cv_cache = (const float*)d_in[21];
  float* out = (float*)d_out;

  float* ws = (float*)d_ws;
  const size_t BDS = (size_t)B_ * D_ * S_;        // 524288
  float* X = ws;                                   // (B,D,S)
  float* Hb = X + BDS;                             // normalized activations
  float* Q = Hb + BDS;                             // q / cq (B,2048,S)
  float* Attn = Q + BDS;                           // attention output (B,2048,S)
  float* Kb = Attn + BDS;                          // (B,512,S)
  float* Vb = Kb + (size_t)B_ * 512 * S_;          // (B,512,S)
  float* Pbuf = Vb + (size_t)B_ * 512 * S_;        // scores (B*16,S,512) / gate (B,FF,S)
  float* Up = Pbuf + (size_t)B_ * 16 * S_ * T_;    // up (B,FF,S)
  float* Rsum = Up + (size_t)B_ * FF_ * S_;        // (B,S)
  uint32_t* Ht = (uint32_t*)(Rsum + B_ * S_);      // packed activations (256, K<=8192)

  const float scale = 0.08838834764831845f;  // 1/sqrt(128), HD == HDC

  hipMemcpyAsync(X, x_in, BDS * sizeof(float), hipMemcpyDeviceToDevice, stream);

  auto rms = [&](const float* src, const float* w, float* dst) {
    hipMemsetAsync(Rsum, 0, B_ * S_ * sizeof(float), stream);
    rms_sumsq<<<dim3(16, B_), 256, 0, stream>>>(src, Rsum);
    rms_apply<<<dim3(B_ * D_ * S_ / 256), 256, 0, stream>>>(src, Rsum, w, dst);
  };
  auto pack = [&](const float* src, int K) {
    pack_h<<<dim3(K / 64, B_), 256, 0, stream>>>(src, Ht, K);
  };
  auto mgemm = [&](const float* Wm, float* Outm, int M, int K, int SK, int accum,
                   int zero) {
    if (zero)
      hipMemsetAsync(Outm, 0, (size_t)B_ * M * S_ * sizeof(float), stream);
    gemm_mfma<<<dim3(M / 128, B_, SK), 256, 0, stream>>>(Wm, Ht, Outm, M, K, K / SK,
                                                         accum);
  };

  for (int l = 0; l < L_; l++) {
    // ---- self attention ----
    rms(X, sa_norm + (size_t)l * D_, Hb);
    pack(Hb, D_);
    mgemm(q_w + (size_t)l * D_ * 2048, Q, 2048, D_, 4, 0, 1);
    mgemm(k_w + (size_t)l * D_ * 512, Kb, 512, D_, 8, 0, 1);
    mgemm(v_w + (size_t)l * D_ * 512, Vb, 512, D_, 8, 0, 1);
    rope_q<<<dim3(B_ * 16 * 64 * S_ / 256), 256, 0, stream>>>(Q, positions);
    rope_k_store<<<dim3(B_ * 4 * S_ * 64 / 256), 256, 0, stream>>>(Kb, positions, wptr,
                                                                   k_cache, l);
    store_v<<<dim3(B_ * 4 * 128 * S_ / 256), 256, 0, stream>>>(Vb, wptr, v_cache, l);
    pack(Q, D_);  // Qt into Ht (reuse)
    attn_scores_mfma<<<dim3(4, B_ * 16), 256, 0, stream>>>(
        k_cache + (size_t)l * B_ * HKV_ * A_ * HD_, Ht, Pbuf, maskArr, encLen, wptr,
        scale, 2, A_, 0);
    softmax_rows<<<dim3(B_ * 16 * S_), 128, 0, stream>>>(Pbuf, wptr, 0);
    attn_pv_mfma<<<dim3(B_ * 16), 256, 0, stream>>>(
        v_cache + (size_t)l * B_ * HKV_ * HD_ * A_, Pbuf, Attn, wptr, 2, A_, 0);
    pack(Attn, D_);
    mgemm(o_w + (size_t)l * 2048 * D_, X, D_, 2048, 4, 1, 0);
    // ---- cross attention ----
    rms(X, ca_norm + (size_t)l * D_, Hb);
    pack(Hb, D_);
    mgemm(cq_w + (size_t)l * D_ * 2048, Q, 2048, D_, 4, 0, 1);
    rope_q<<<dim3(B_ * 16 * 64 * S_ / 256), 256, 0, stream>>>(Q, positions);
    pack(Q, D_);  // Qt into Ht
    attn_scores_mfma<<<dim3(4, B_ * 16), 256, 0, stream>>>(
        ck_cache + (size_t)l * B_ * 16 * T_ * HD_, Ht, Pbuf, maskArr, encLen, wptr,
        scale, 0, T_, 1);
    softmax_rows<<<dim3(B_ * 16 * S_), 128, 0, stream>>>(Pbuf, wptr, 1);
    attn_pv_mfma<<<dim3(B_ * 16), 256, 0, stream>>>(
        cv_cache + (size_t)l * B_ * 16 * HD_ * T_, Pbuf, Attn, wptr, 0, T_, 1);
    pack(Attn, D_);
    mgemm(co_w + (size_t)l * 2048 * D_, X, D_, 2048, 4, 1, 0);
    // ---- MLP ----
    rms(X, mlp_norm + (size_t)l * D_, Hb);
    pack(Hb, D_);
    mgemm(wg_w + (size_t)l * D_ * FF_, Pbuf, FF_, D_, 2, 0, 1);
    mgemm(wu_w + (size_t)l * D_ * FF_, Up, FF_, D_, 2, 0, 1);
    silu_mul<<<dim3(B_ * FF_ * S_ / 256), 256, 0, stream>>>(Pbuf, Up);
    pack(Pbuf, FF_);
    mgemm(wd_w + (size_t)l * FF_ * D_, X, D_, FF_, 8, 1, 0);
  }
  // ---- final norm -> d_out ----
  rms(X, fin_norm, out);
}

// Round 5
// 1630.206 us; speedup vs baseline: 1.3509x; 1.1157x over previous
//
#include <hip/hip_runtime.h>
#include <math.h>
#include <stdint.h>

namespace {

constexpr int B_ = 2, D_ = 2048, S_ = 128, A_ = 1536, T_ = 512;
constexpr int HQ_ = 16, HKV_ = 4, HD_ = 128, FF_ = 8192, L_ = 2;
constexpr float NEG_ = -30000.0f, EPS_ = 1e-5f;

typedef __attribute__((ext_vector_type(4))) float f32x4;
typedef __attribute__((ext_vector_type(8))) short s16x8;  // 8 bf16 (4 VGPRs)

// split fp32 -> (hi bf16, lo bf16) packed in one u32: low16=hi, high16=lo.
__device__ __forceinline__ uint32_t bf16pair(float x) {
  uint32_t xi = __float_as_uint(x);
  uint32_t hi = (xi + 0x7FFFu + ((xi >> 16) & 1u)) >> 16;
  float hf = __uint_as_float(hi << 16);
  float r = x - hf;  // exact
  uint32_t ri = __float_as_uint(r);
  uint32_t lo = (ri + 0x7FFFu + ((ri >> 16) & 1u)) >> 16;
  return (hi & 0xFFFFu) | (lo << 16);
}

// unpack 8 interleaved u32 {hi,lo} -> hi-fragment and lo-fragment (bf16x8)
__device__ __forceinline__ void unpack8(uint4 q0, uint4 q1, s16x8& hi, s16x8& lo) {
  union U { uint32_t w[4]; s16x8 v; };
  U h, l;
  uint32_t u[8] = {q0.x, q0.y, q0.z, q0.w, q1.x, q1.y, q1.z, q1.w};
#pragma unroll
  for (int r = 0; r < 4; r++) {
    h.w[r] = __builtin_amdgcn_perm(u[2 * r + 1], u[2 * r], 0x05040100u);
    l.w[r] = __builtin_amdgcn_perm(u[2 * r + 1], u[2 * r], 0x07060302u);
  }
  hi = h.v;
  lo = l.v;
}

__device__ __forceinline__ void rope_angles(int pos, int i, float& sn, float& cs) {
  float inv_freq = powf(10000.0f, -(float)i * (1.0f / 64.0f));
  float ang = (float)pos * inv_freq;
  sn = sinf(ang);
  cs = cosf(ang);
}

// ---------------- RMSNorm sum of squares ----------------
__global__ __launch_bounds__(256) void rms_sumsq(const float* __restrict__ x,
                                                 float* __restrict__ rsum) {
  int b = blockIdx.y, c = blockIdx.x;
  int tid = threadIdx.x;
  int s = tid & 127, dd = tid >> 7;
  const float* xp = x + ((size_t)b * D_ + c * 128) * S_ + s;
  float acc = 0.f;
  for (int d = dd; d < 128; d += 2) {
    float v = xp[(size_t)d * S_];
    acc += v * v;
  }
  __shared__ float lds[256];
  lds[tid] = acc;
  __syncthreads();
  if (dd == 0) atomicAdd(&rsum[b * S_ + s], lds[s] + lds[128 + s]);
}

// final-norm apply (fp32 out)
__global__ __launch_bounds__(256) void rms_apply(const float* __restrict__ x,
                                                 const float* __restrict__ rsum,
                                                 const float* __restrict__ w,
                                                 float* __restrict__ out) {
  int i = blockIdx.x * 256 + threadIdx.x;
  int s = i & (S_ - 1);
  int d = (i / S_) & (D_ - 1);
  int b = i / (D_ * S_);
  float inv = rsqrtf(rsum[b * S_ + s] * (1.0f / D_) + EPS_);
  out[i] = x[i] * inv * w[d];
}

// ---------------- pack family: [b][K][S] fp32 -> Ht[b*128+s][K] u32{hi,lo} ---
// plain pack (for attention output)
__global__ __launch_bounds__(256) void pack_h(const float* __restrict__ H,
                                              uint32_t* __restrict__ Ht, int K) {
  int b = blockIdx.y;
  int k0 = blockIdx.x * 64;
  __shared__ uint32_t t[128][65];
  int tid = threadIdx.x;
  int s = tid & 127, kk = tid >> 7;
  const float* Hp = H + ((size_t)b * K + k0) * S_ + s;
  for (int k = kk; k < 64; k += 2) t[s][k] = bf16pair(Hp[(size_t)k * S_]);
  __syncthreads();
  int k2 = tid & 63, s2 = tid >> 6;
  uint32_t* Op = Ht + (size_t)(b * S_) * K + k0 + k2;
  for (int ss = s2; ss < 128; ss += 4) Op[(size_t)ss * K] = t[ss][k2];
}

// fused RMSNorm-apply + pack (K == D_)
__global__ __launch_bounds__(256) void pack_rms(const float* __restrict__ H,
                                                const float* __restrict__ rsum,
                                                const float* __restrict__ w,
                                                uint32_t* __restrict__ Ht) {
  int b = blockIdx.y;
  int k0 = blockIdx.x * 64;
  __shared__ uint32_t t[128][65];
  int tid = threadIdx.x;
  int s = tid & 127, kk = tid >> 7;
  const float* Hp = H + ((size_t)b * D_ + k0) * S_ + s;
  float inv = rsqrtf(rsum[b * S_ + s] * (1.0f / D_) + EPS_);
  for (int k = kk; k < 64; k += 2)
    t[s][k] = bf16pair(Hp[(size_t)k * S_] * inv * w[k0 + k]);
  __syncthreads();
  int k2 = tid & 63, s2 = tid >> 6;
  uint32_t* Op = Ht + (size_t)(b * S_) * D_ + k0 + k2;
  for (int ss = s2; ss < 128; ss += 4) Op[(size_t)ss * D_] = t[ss][k2];
}

// fused RoPE + pack of Q from QKV buffer (row-stride 3072 per b).
// grid (32, B): c = 2*h + half; k0 = c*64 = h*128 + half*64.
__global__ __launch_bounds__(256) void pack_rope(const float* __restrict__ QKV,
                                                 const int* __restrict__ positions,
                                                 uint32_t* __restrict__ Ht) {
  int b = blockIdx.y, c = blockIdx.x;
  int h = c >> 1, half = c & 1, k0 = c * 64;
  __shared__ uint32_t t[128][65];
  int tid = threadIdx.x;
  int s = tid & 127, kk = tid >> 7;
  const float* Qp = QKV + ((size_t)b * 3072 + h * 128) * S_ + s;
  int pos = positions[b * S_ + s];
  for (int i = kk; i < 64; i += 2) {
    float sn, cs;
    rope_angles(pos, i, sn, cs);
    float x1 = Qp[(size_t)i * S_], x2 = Qp[(size_t)(i + 64) * S_];
    t[s][i] = bf16pair(half == 0 ? x1 * cs - x2 * sn : x2 * cs + x1 * sn);
  }
  __syncthreads();
  int k2 = tid & 63, s2 = tid >> 6;
  uint32_t* Op = Ht + (size_t)(b * S_) * D_ + k0 + k2;
  for (int ss = s2; ss < 128; ss += 4) Op[(size_t)ss * D_] = t[ss][k2];
}

// fused silu(gate)*up + pack from GU buffer (gate at m, up at 8192+m), K=FF
__global__ __launch_bounds__(256) void pack_silu(const float* __restrict__ GU,
                                                 uint32_t* __restrict__ Ht) {
  int b = blockIdx.y;
  int k0 = blockIdx.x * 64;
  __shared__ uint32_t t[128][65];
  int tid = threadIdx.x;
  int s = tid & 127, kk = tid >> 7;
  const float* Gp = GU + ((size_t)b * 16384 + k0) * S_ + s;
  const float* Up2 = Gp + (size_t)8192 * S_;
  for (int k = kk; k < 64; k += 2) {
    float g = Gp[(size_t)k * S_], u = Up2[(size_t)k * S_];
    t[s][k] = bf16pair(g / (1.f + expf(-g)) * u);
  }
  __syncthreads();
  int k2 = tid & 63, s2 = tid >> 6;
  uint32_t* Op = Ht + (size_t)(b * S_) * FF_ + k0 + k2;
  for (int ss = s2; ss < 128; ss += 4) Op[(size_t)ss * FF_] = t[ss][k2];
}

// ---------------- split-bf16 MFMA GEMM ----------------
// C[b, m, s] (+)= sum_k W[k*Mw + mW] * H[b, k, s]; Out row stride MS per b.
// W selected per m-tile: tile < tb1 -> W0, < tb2 -> W1, else W2.
__global__ __launch_bounds__(256, 2) void gemm_mfma(
    const float* __restrict__ W0, const float* __restrict__ W1,
    const float* __restrict__ W2, int tb1, int tb2, int Mw0, int Mw1, int Mw2,
    const uint32_t* __restrict__ Ht, float* __restrict__ Out, int MS, int K,
    int KC, int accum) {
  __shared__ uint32_t As[128 * 32];
  __shared__ uint32_t Bs[128 * 32];
  int mt = blockIdx.x;
  int m0 = mt * 128;
  const float* W;
  int Mw, mW;
  if (mt < tb1) {
    W = W0; Mw = Mw0; mW = m0;
  } else if (mt < tb2) {
    W = W1; Mw = Mw1; mW = m0 - tb1 * 128;
  } else {
    W = W2; Mw = Mw2; mW = m0 - tb2 * 128;
  }
  int b = blockIdx.y;
  int k0 = blockIdx.z * KC;
  int tid = threadIdx.x;
  int lane = tid & 63, wave = tid >> 6;
  int wm = (wave >> 1) * 64, wn = (wave & 1) * 64;
  int lr = lane & 15, lg = lane >> 4;
  int a_k4 = (tid >> 5) * 4;
  int a_m4 = (tid & 31) * 4;
  int ag = a_k4 >> 2;
  int b_g = tid & 3;
  int b_s = tid >> 2;
  const uint32_t* HtB = Ht + (size_t)(b * S_) * K;

  f32x4 acc[4][4];
  f32x4 zero = {0.f, 0.f, 0.f, 0.f};
#pragma unroll
  for (int i = 0; i < 4; i++)
#pragma unroll
    for (int j = 0; j < 4; j++) acc[i][j] = zero;

  for (int kk = k0; kk < k0 + KC; kk += 32) {
    const float* Wp = W + (size_t)(kk + a_k4) * Mw + (mW + a_m4);
    float4 w0 = *(const float4*)(Wp);
    float4 w1 = *(const float4*)(Wp + (size_t)Mw);
    float4 w2 = *(const float4*)(Wp + 2 * (size_t)Mw);
    float4 w3 = *(const float4*)(Wp + 3 * (size_t)Mw);
    {
      uint4 u;
      int m = a_m4;
      u.x = bf16pair(w0.x); u.y = bf16pair(w1.x); u.z = bf16pair(w2.x); u.w = bf16pair(w3.x);
      *(uint4*)&As[m * 32 + ((ag ^ (m & 7)) << 2)] = u;
      m = a_m4 + 1;
      u.x = bf16pair(w0.y); u.y = bf16pair(w1.y); u.z = bf16pair(w2.y); u.w = bf16pair(w3.y);
      *(uint4*)&As[m * 32 + ((ag ^ (m & 7)) << 2)] = u;
      m = a_m4 + 2;
      u.x = bf16pair(w0.z); u.y = bf16pair(w1.z); u.z = bf16pair(w2.z); u.w = bf16pair(w3.z);
      *(uint4*)&As[m * 32 + ((ag ^ (m & 7)) << 2)] = u;
      m = a_m4 + 3;
      u.x = bf16pair(w0.w); u.y = bf16pair(w1.w); u.z = bf16pair(w2.w); u.w = bf16pair(w3.w);
      *(uint4*)&As[m * 32 + ((ag ^ (m & 7)) << 2)] = u;
    }
#pragma unroll
    for (int c = 0; c < 2; c++)
#pragma unroll
      for (int d = 0; d < 2; d++) {
        int s = b_s + c * 64;
        int g = b_g + d * 4;
        uint4 v = *(const uint4*)&HtB[(size_t)s * K + kk + g * 4];
        *(uint4*)&Bs[s * 32 + ((g ^ (s & 7)) << 2)] = v;
      }
    __syncthreads();
    s16x8 ah[4], al[4], bhf[4], blf[4];
#pragma unroll
    for (int mi = 0; mi < 4; mi++) {
      int row = wm + mi * 16 + lr;
      const uint32_t* p = &As[row * 32];
      uint4 q0 = *(const uint4*)&p[(((lg << 1) ^ (row & 7)) << 2)];
      uint4 q1 = *(const uint4*)&p[((((lg << 1) | 1) ^ (row & 7)) << 2)];
      unpack8(q0, q1, ah[mi], al[mi]);
    }
#pragma unroll
    for (int ni = 0; ni < 4; ni++) {
      int row = wn + ni * 16 + lr;
      const uint32_t* p = &Bs[row * 32];
      uint4 q0 = *(const uint4*)&p[(((lg << 1) ^ (row & 7)) << 2)];
      uint4 q1 = *(const uint4*)&p[((((lg << 1) | 1) ^ (row & 7)) << 2)];
      unpack8(q0, q1, bhf[ni], blf[ni]);
    }
#pragma unroll
    for (int mi = 0; mi < 4; mi++)
#pragma unroll
      for (int ni = 0; ni < 4; ni++)
        acc[mi][ni] = __builtin_amdgcn_mfma_f32_16x16x32_bf16(ah[mi], bhf[ni],
                                                              acc[mi][ni], 0, 0, 0);
#pragma unroll
    for (int mi = 0; mi < 4; mi++)
#pragma unroll
      for (int ni = 0; ni < 4; ni++)
        acc[mi][ni] = __builtin_amdgcn_mfma_f32_16x16x32_bf16(ah[mi], blf[ni],
                                                              acc[mi][ni], 0, 0, 0);
#pragma unroll
    for (int mi = 0; mi < 4; mi++)
#pragma unroll
      for (int ni = 0; ni < 4; ni++)
        acc[mi][ni] = __builtin_amdgcn_mfma_f32_16x16x32_bf16(al[mi], bhf[ni],
                                                              acc[mi][ni], 0, 0, 0);
    __syncthreads();
  }
  if (gridDim.z == 1) {
#pragma unroll
    for (int mi = 0; mi < 4; mi++)
#pragma unroll
      for (int ni = 0; ni < 4; ni++) {
        int m = m0 + wm + mi * 16 + lg * 4;
        int sI = wn + ni * 16 + lr;
        size_t base = ((size_t)b * MS + m) * S_ + sI;
#pragma unroll
        for (int r = 0; r < 4; r++) {
          float v = acc[mi][ni][r];
          if (accum) v += Out[base + (size_t)r * S_];
          Out[base + (size_t)r * S_] = v;
        }
      }
  } else {
#pragma unroll
    for (int mi = 0; mi < 4; mi++)
#pragma unroll
      for (int ni = 0; ni < 4; ni++) {
        int m = m0 + wm + mi * 16 + lg * 4;
        int sI = wn + ni * 16 + lr;
        size_t base = ((size_t)b * MS + m) * S_ + sI;
#pragma unroll
        for (int r = 0; r < 4; r++)
          atomicAdd(&Out[base + (size_t)r * S_], acc[mi][ni][r]);
      }
  }
}

// ---------------- MFMA attention scores ----------------
__global__ __launch_bounds__(256, 2) void attn_scores_mfma(
    const float* __restrict__ key, const uint32_t* __restrict__ Qt,
    float* __restrict__ P, const float* __restrict__ maskArr,
    const int* __restrict__ encLen, const int* __restrict__ wptr, float scale,
    int gshift, int AN, int mode) {
  int bh = blockIdx.y;
  int b = bh >> 4, h = bh & 15;
  int kvh = h >> gshift, nkv = 16 >> gshift;
  int Aeff = (mode == 0) ? (wptr[0] + S_) : T_;
  int a0 = blockIdx.x * 128;
  if (a0 >= Aeff) return;
  __shared__ uint32_t As[128 * 32];  // rows = a
  __shared__ uint32_t Bs[128 * 32];  // rows = s
  const float* kbase =
      key + (size_t)(b * nkv + kvh) * AN * HD_ + (size_t)a0 * HD_;
  const uint32_t* qbase = Qt + (size_t)(b * S_) * D_ + h * HD_;  // row stride D_
  int tid = threadIdx.x, lane = tid & 63, wave = tid >> 6;
  int wm = (wave >> 1) * 64, wn = (wave & 1) * 64;
  int lr = lane & 15, lg = lane >> 4;
  int g_ = tid & 3, r_ = tid >> 2;

  f32x4 acc[4][4];
  f32x4 zero = {0.f, 0.f, 0.f, 0.f};
#pragma unroll
  for (int i = 0; i < 4; i++)
#pragma unroll
    for (int j = 0; j < 4; j++) acc[i][j] = zero;

  for (int hc = 0; hc < HD_; hc += 32) {
#pragma unroll
    for (int c = 0; c < 2; c++)
#pragma unroll
      for (int d = 0; d < 2; d++) {
        int row = r_ + c * 64, g = g_ + d * 4;
        float4 v = *(const float4*)&kbase[(size_t)row * HD_ + hc + g * 4];
        uint4 u;
        u.x = bf16pair(v.x); u.y = bf16pair(v.y);
        u.z = bf16pair(v.z); u.w = bf16pair(v.w);
        *(uint4*)&As[row * 32 + ((g ^ (row & 7)) << 2)] = u;
        uint4 q = *(const uint4*)&qbase[(size_t)row * D_ + hc + g * 4];
        *(uint4*)&Bs[row * 32 + ((g ^ (row & 7)) << 2)] = q;
      }
    __syncthreads();
    s16x8 ah[4], al[4], bhf[4], blf[4];
#pragma unroll
    for (int mi = 0; mi < 4; mi++) {
      int row = wm + mi * 16 + lr;
      const uint32_t* p = &As[row * 32];
      uint4 q0 = *(const uint4*)&p[(((lg << 1) ^ (row & 7)) << 2)];
      uint4 q1 = *(const uint4*)&p[((((lg << 1) | 1) ^ (row & 7)) << 2)];
      unpack8(q0, q1, ah[mi], al[mi]);
    }
#pragma unroll
    for (int ni = 0; ni < 4; ni++) {
      int row = wn + ni * 16 + lr;
      const uint32_t* p = &Bs[row * 32];
      uint4 q0 = *(const uint4*)&p[(((lg << 1) ^ (row & 7)) << 2)];
      uint4 q1 = *(const uint4*)&p[((((lg << 1) | 1) ^ (row & 7)) << 2)];
      unpack8(q0, q1, bhf[ni], blf[ni]);
    }
#pragma unroll
    for (int mi = 0; mi < 4; mi++)
#pragma unroll
      for (int ni = 0; ni < 4; ni++)
        acc[mi][ni] = __builtin_amdgcn_mfma_f32_16x16x32_bf16(ah[mi], bhf[ni],
                                                              acc[mi][ni], 0, 0, 0);
#pragma unroll
    for (int mi = 0; mi < 4; mi++)
#pragma unroll
      for (int ni = 0; ni < 4; ni++)
        acc[mi][ni] = __builtin_amdgcn_mfma_f32_16x16x32_bf16(ah[mi], blf[ni],
                                                              acc[mi][ni], 0, 0, 0);
#pragma unroll
    for (int mi = 0; mi < 4; mi++)
#pragma unroll
      for (int ni = 0; ni < 4; ni++)
        acc[mi][ni] = __builtin_amdgcn_mfma_f32_16x16x32_bf16(al[mi], bhf[ni],
                                                              acc[mi][ni], 0, 0, 0);
    __syncthreads();
  }
  int eLen = (mode == 0) ? 0 : encLen[b];
#pragma unroll
  for (int mi = 0; mi < 4; mi++)
#pragma unroll
    for (int ni = 0; ni < 4; ni++) {
      int ab = a0 + wm + mi * 16 + lg * 4;
      int s = wn + ni * 16 + lr;
      float* Pp = P + ((size_t)bh * S_ + s) * T_;
      const float* Mp = maskArr + ((size_t)b * S_ + s) * A_;
#pragma unroll
      for (int r = 0; r < 4; r++) {
        int a = ab + r;
        if (a < Aeff) {
          float mval = (mode == 0) ? Mp[a] : ((a < eLen) ? 0.f : NEG_);
          Pp[a] = acc[mi][ni][r] * scale + mval;
        }
      }
    }
}

// ---------------- MFMA attention PV ----------------
__global__ __launch_bounds__(256, 2) void attn_pv_mfma(
    const float* __restrict__ val, const float* __restrict__ P,
    float* __restrict__ out, const int* __restrict__ wptr, int gshift, int AN,
    int mode) {
  int bh = blockIdx.x;
  int b = bh >> 4, h = bh & 15;
  int kvh = h >> gshift, nkv = 16 >> gshift;
  int Aeff = (mode == 0) ? (wptr[0] + S_) : T_;
  int nk = (Aeff + 31) >> 5;
  __shared__ uint32_t As[128 * 32];  // rows = hd
  __shared__ uint32_t Bs[128 * 32];  // rows = s
  const float* vbase = val + (size_t)(b * nkv + kvh) * HD_ * AN;
  const float* Pb = P + (size_t)bh * S_ * T_;
  int tid = threadIdx.x, lane = tid & 63, wave = tid >> 6;
  int wm = (wave >> 1) * 64, wn = (wave & 1) * 64;
  int lr = lane & 15, lg = lane >> 4;
  int g_ = tid & 3, r_ = tid >> 2;

  f32x4 acc[4][4];
  f32x4 zero = {0.f, 0.f, 0.f, 0.f};
#pragma unroll
  for (int i = 0; i < 4; i++)
#pragma unroll
    for (int j = 0; j < 4; j++) acc[i][j] = zero;

  for (int kkt = 0; kkt < nk; kkt++) {
    int a0c = kkt * 32;
#pragma unroll
    for (int c = 0; c < 2; c++)
#pragma unroll
      for (int d = 0; d < 2; d++) {
        int row = r_ + c * 64, g = g_ + d * 4;
        int a = a0c + g * 4;
        float4 v = *(const float4*)&vbase[(size_t)row * AN + a];
        uint4 u;
        u.x = bf16pair(v.x); u.y = bf16pair(v.y);
        u.z = bf16pair(v.z); u.w = bf16pair(v.w);
        *(uint4*)&As[row * 32 + ((g ^ (row & 7)) << 2)] = u;
        float4 p4 = *(const float4*)&Pb[(size_t)row * T_ + a];
        uint4 up;
        up.x = (a + 0 < Aeff) ? bf16pair(p4.x) : 0u;
        up.y = (a + 1 < Aeff) ? bf16pair(p4.y) : 0u;
        up.z = (a + 2 < Aeff) ? bf16pair(p4.z) : 0u;
        up.w = (a + 3 < Aeff) ? bf16pair(p4.w) : 0u;
        *(uint4*)&Bs[row * 32 + ((g ^ (row & 7)) << 2)] = up;
      }
    __syncthreads();
    s16x8 ah[4], al[4], bhf[4], blf[4];
#pragma unroll
    for (int mi = 0; mi < 4; mi++) {
      int row = wm + mi * 16 + lr;
      const uint32_t* p = &As[row * 32];
      uint4 q0 = *(const uint4*)&p[(((lg << 1) ^ (row & 7)) << 2)];
      uint4 q1 = *(const uint4*)&p[((((lg << 1) | 1) ^ (row & 7)) << 2)];
      unpack8(q0, q1, ah[mi], al[mi]);
    }
#pragma unroll
    for (int ni = 0; ni < 4; ni++) {
      int row = wn + ni * 16 + lr;
      const uint32_t* p = &Bs[row * 32];
      uint4 q0 = *(const uint4*)&p[(((lg << 1) ^ (row & 7)) << 2)];
      uint4 q1 = *(const uint4*)&p[((((lg << 1) | 1) ^ (row & 7)) << 2)];
      unpack8(q0, q1, bhf[ni], blf[ni]);
    }
#pragma unroll
    for (int mi = 0; mi < 4; mi++)
#pragma unroll
      for (int ni = 0; ni < 4; ni++)
        acc[mi][ni] = __builtin_amdgcn_mfma_f32_16x16x32_bf16(ah[mi], bhf[ni],
                                                              acc[mi][ni], 0, 0, 0);
#pragma unroll
    for (int mi = 0; mi < 4; mi++)
#pragma unroll
      for (int ni = 0; ni < 4; ni++)
        acc[mi][ni] = __builtin_amdgcn_mfma_f32_16x16x32_bf16(ah[mi], blf[ni],
                                                              acc[mi][ni], 0, 0, 0);
#pragma unroll
    for (int mi = 0; mi < 4; mi++)
#pragma unroll
      for (int ni = 0; ni < 4; ni++)
        acc[mi][ni] = __builtin_amdgcn_mfma_f32_16x16x32_bf16(al[mi], bhf[ni],
                                                              acc[mi][ni], 0, 0, 0);
    __syncthreads();
  }
#pragma unroll
  for (int mi = 0; mi < 4; mi++)
#pragma unroll
    for (int ni = 0; ni < 4; ni++) {
      int hd = wm + mi * 16 + lg * 4;
      int s = wn + ni * 16 + lr;
      size_t base = ((size_t)bh * HD_ + hd) * S_ + s;
#pragma unroll
      for (int r = 0; r < 4; r++) out[base + (size_t)r * S_] = acc[mi][ni][r];
    }
}

// ---------------- KV cache writes (from QKV buffer) ----------------
__global__ __launch_bounds__(256) void rope_k_store(const float* __restrict__ QKV,
                                                    const int* __restrict__ positions,
                                                    const int* __restrict__ wptr,
                                                    float* __restrict__ k_cache, int l) {
  int idx = blockIdx.x * 256 + threadIdx.x;
  int i = idx & 63;
  int s = (idx >> 6) & 127;
  int kv = (idx >> 13) & 3;
  int b = idx >> 15;
  int w = wptr[0];
  float sn, cs;
  rope_angles(positions[b * S_ + s], i, sn, cs);
  size_t i1 = ((size_t)b * 3072 + 2048 + kv * 128 + i) * S_ + s;
  float x1 = QKV[i1], x2 = QKV[i1 + (size_t)64 * S_];
  size_t o = ((size_t)((l * B_ + b) * HKV_ + kv) * A_ + (w + s)) * HD_ + i;
  k_cache[o] = x1 * cs - x2 * sn;
  k_cache[o + 64] = x2 * cs + x1 * sn;
}

__global__ __launch_bounds__(256) void store_v(const float* __restrict__ QKV,
                                               const int* __restrict__ wptr,
                                               float* __restrict__ v_cache, int l) {
  int idx = blockIdx.x * 256 + threadIdx.x;
  int s = idx & 127;
  int hd = (idx >> 7) & 127;
  int kv = (idx >> 14) & 3;
  int b = idx >> 16;
  int w = wptr[0];
  float v = QKV[((size_t)b * 3072 + 2560 + kv * 128 + hd) * S_ + s];
  v_cache[((size_t)((l * B_ + b) * HKV_ + kv) * HD_ + hd) * A_ + w + s] = v;
}

// ---------------- softmax ----------------
__global__ __launch_bounds__(128) void softmax_rows(float* __restrict__ P,
                                                    const int* __restrict__ wptr,
                                                    int mode) {
  int row = blockIdx.x;
  int Aeff = (mode == 0) ? (wptr[0] + S_) : T_;
  float* p = P + (size_t)row * T_;
  int tid = threadIdx.x;
  float v[4];
  int cnt = 0;
  float m = -1e30f;
  for (int a = tid; a < Aeff; a += 128) {
    float t = p[a];
    v[cnt++] = t;
    m = fmaxf(m, t);
  }
  __shared__ float r0[2], r1[2];
  for (int off = 32; off > 0; off >>= 1) m = fmaxf(m, __shfl_down(m, off));
  if ((tid & 63) == 0) r0[tid >> 6] = m;
  __syncthreads();
  m = fmaxf(r0[0], r0[1]);
  float sum = 0.f;
  for (int i = 0; i < cnt; i++) {
    v[i] = expf(v[i] - m);
    sum += v[i];
  }
  for (int off = 32; off > 0; off >>= 1) sum += __shfl_down(sum, off);
  if ((tid & 63) == 0) r1[tid >> 6] = sum;
  __syncthreads();
  float inv = 1.f / (r1[0] + r1[1]);
  cnt = 0;
  for (int a = tid; a < Aeff; a += 128) p[a] = v[cnt++] * inv;
}

}  // namespace

extern "C" void kernel_launch(void* const* d_in, const int* in_sizes, int n_in,
                              void* d_out, int out_size, void* d_ws, size_t ws_size,
                              hipStream_t stream) {
  const float* x_in = (const float*)d_in[0];
  const int* positions = (const int*)d_in[1];
  const int* wptr = (const int*)d_in[2];
  const float* maskArr = (const float*)d_in[3];
  const int* encLen = (const int*)d_in[4];
  const float* q_w = (const float*)d_in[5];
  const float* k_w = (const float*)d_in[6];
  const float* v_w = (const float*)d_in[7];
  const float* o_w = (const float*)d_in[8];
  const float* cq_w = (const float*)d_in[9];
  const float* co_w = (const float*)d_in[10];
  const float* sa_norm = (const float*)d_in[11];
  const float* ca_norm = (const float*)d_in[12];
  const float* mlp_norm = (const float*)d_in[13];
  const float* fin_norm = (const float*)d_in[14];
  const float* wg_w = (const float*)d_in[15];
  const float* wu_w = (const float*)d_in[16];
  const float* wd_w = (const float*)d_in[17];
  float* k_cache = (float*)d_in[18];
  float* v_cache = (float*)d_in[19];
  const float* ck_cache = (const float*)d_in[20];
  const float* cv_cache = (const float*)d_in[21];
  float* out = (float*)d_out;

  float* ws = (float*)d_ws;
  const size_t BDS = (size_t)B_ * D_ * S_;            // 524288
  float* X = ws;                                       // (B,D,S)       2 MB
  float* QKV = X + BDS;                                // (B,3072,S)    3 MB
  float* Attn = QKV + (size_t)B_ * 3072 * S_;          // (B,2048,S)    2 MB
  float* GU = Attn + BDS;                              // (B,16384,S) 16.8 MB; P aliases
  float* Pbuf = GU;                                    // scores (B*16,S,T)
  float* Rsum = GU + (size_t)B_ * 16384 * S_;          // (B,S)
  uint32_t* Ht = (uint32_t*)(Rsum + 1024);             // packed acts (256, K<=8192)

  const float scale = 0.08838834764831845f;  // 1/sqrt(128), HD == HDC
  const int BIG = 1 << 30;

  hipMemcpyAsync(X, x_in, BDS * sizeof(float), hipMemcpyDeviceToDevice, stream);

  auto norm_pack = [&](const float* src, const float* w) {
    hipMemsetAsync(Rsum, 0, B_ * S_ * sizeof(float), stream);
    rms_sumsq<<<dim3(16, B_), 256, 0, stream>>>(src, Rsum);
    pack_rms<<<dim3(32, B_), 256, 0, stream>>>(src, Rsum, w, Ht);
  };

  for (int l = 0; l < L_; l++) {
    // ---- self attention ----
    norm_pack(X, sa_norm + (size_t)l * D_);
    hipMemsetAsync(QKV, 0, (size_t)B_ * 3072 * S_ * sizeof(float), stream);
    gemm_mfma<<<dim3(24, B_, 8), 256, 0, stream>>>(
        q_w + (size_t)l * D_ * 2048, k_w + (size_t)l * D_ * 512,
        v_w + (size_t)l * D_ * 512, 16, 20, 2048, 512, 512, Ht, QKV, 3072, D_,
        D_ / 8, 0);
    rope_k_store<<<dim3(B_ * 4 * 128 * 64 / 256), 256, 0, stream>>>(
        QKV, positions, wptr, k_cache, l);
    store_v<<<dim3(B_ * 4 * 128 * 128 / 256), 256, 0, stream>>>(QKV, wptr, v_cache,
                                                                l);
    pack_rope<<<dim3(32, B_), 256, 0, stream>>>(QKV, positions, Ht);
    attn_scores_mfma<<<dim3(4, B_ * 16), 256, 0, stream>>>(
        k_cache + (size_t)l * B_ * HKV_ * A_ * HD_, Ht, Pbuf, maskArr, encLen, wptr,
        scale, 2, A_, 0);
    softmax_rows<<<dim3(B_ * 16 * S_), 128, 0, stream>>>(Pbuf, wptr, 0);
    attn_pv_mfma<<<dim3(B_ * 16), 256, 0, stream>>>(
        v_cache + (size_t)l * B_ * HKV_ * HD_ * A_, Pbuf, Attn, wptr, 2, A_, 0);
    pack_h<<<dim3(32, B_), 256, 0, stream>>>(Attn, Ht, D_);
    gemm_mfma<<<dim3(16, B_, 8), 256, 0, stream>>>(
        o_w + (size_t)l * 2048 * D_, nullptr, nullptr, BIG, BIG, 2048, 0, 0, Ht, X,
        2048, 2048, 2048 / 8, 1);
    // ---- cross attention ----
    norm_pack(X, ca_norm + (size_t)l * D_);
    hipMemsetAsync(QKV, 0, (size_t)B_ * 3072 * S_ * sizeof(float), stream);
    gemm_mfma<<<dim3(16, B_, 8), 256, 0, stream>>>(
        cq_w + (size_t)l * D_ * 2048, nullptr, nullptr, BIG, BIG, 2048, 0, 0, Ht,
        QKV, 3072, D_, D_ / 8, 0);
    pack_rope<<<dim3(32, B_), 256, 0, stream>>>(QKV, positions, Ht);
    attn_scores_mfma<<<dim3(4, B_ * 16), 256, 0, stream>>>(
        ck_cache + (size_t)l * B_ * 16 * T_ * HD_, Ht, Pbuf, maskArr, encLen, wptr,
        scale, 0, T_, 1);
    softmax_rows<<<dim3(B_ * 16 * S_), 128, 0, stream>>>(Pbuf, wptr, 1);
    attn_pv_mfma<<<dim3(B_ * 16), 256, 0, stream>>>(
        cv_cache + (size_t)l * B_ * 16 * HD_ * T_, Pbuf, Attn, wptr, 0, T_, 1);
    pack_h<<<dim3(32, B_), 256, 0, stream>>>(Attn, Ht, D_);
    gemm_mfma<<<dim3(16, B_, 8), 256, 0, stream>>>(
        co_w + (size_t)l * 2048 * D_, nullptr, nullptr, BIG, BIG, 2048, 0, 0, Ht, X,
        2048, 2048, 2048 / 8, 1);
    // ---- MLP ----
    norm_pack(X, mlp_norm + (size_t)l * D_);
    hipMemsetAsync(GU, 0, (size_t)B_ * 16384 * S_ * sizeof(float), stream);
    gemm_mfma<<<dim3(128, B_, 2), 256, 0, stream>>>(
        wg_w + (size_t)l * D_ * FF_, wu_w + (size_t)l * D_ * FF_, nullptr, 64, BIG,
        8192, 8192, 0, Ht, GU, 16384, D_, D_ / 2, 0);
    pack_silu<<<dim3(128, B_), 256, 0, stream>>>(GU, Ht);
    gemm_mfma<<<dim3(16, B_, 8), 256, 0, stream>>>(
        wd_w + (size_t)l * FF_ * D_, nullptr, nullptr, BIG, BIG, 2048, 0, 0, Ht, X,
        2048, FF_, FF_ / 8, 1);
  }
  // ---- final norm -> d_out ----
  hipMemsetAsync(Rsum, 0, B_ * S_ * sizeof(float), stream);
  rms_sumsq<<<dim3(16, B_), 256, 0, stream>>>(X, Rsum);
  rms_apply<<<dim3(B_ * D_ * S_ / 256), 256, 0, stream>>>(X, Rsum, fin_norm, out);
}